// Round 7
// baseline (589.499 us; speedup 1.0000x reference)
//
#include <hip/hip_runtime.h>
#include <hip/hip_bf16.h>
#include <math.h>

// Problem constants (structure of the model; N/E derived at runtime)
#define NPG   100
#define FIN   128
#define KK    30
#define NC    10
#define FC    97    // concat feature width: 32+32+32+1
#define XCS   100   // padded row stride for the concat buffer (16B-aligned rows)

#define BKT_SHIFT 6          // 64 nodes per bucket
#define BKT_N     64
#define NBMAX     2048       // supports N up to 131072 (also the src-packing limit 2^17)
#define CHA       2048       // edges per block in sort pass A
#define NBLKMAX   2048       // supports E up to 2048*2048 = 4.19M
#define BCAP      2560       // LDS-cached edges per bucket in pass B (mean 2048, +11 sigma)

__device__ inline void fma4(float4& a, float s, const float4& w) {
    a.x += s * w.x; a.y += s * w.y; a.z += s * w.z; a.w += s * w.w;
}
__device__ inline void scl4(float4& a, float s) { a.x *= s; a.y *= s; a.z *= s; a.w *= s; }

// ---------------- CSR build: transpose bucket sort ----------------
// sortA: per-block counting sort by 64-node bucket; pass 1 counts (LDS hist),
//        scan emits packed (local_base | count<<16) into cntmat[k][b] and
//        accumulates colsum[b]; pass 2 scatters packed (src | d_local<<17)
//        DIRECTLY into the block's own contiguous 8KB ebuf chunk (L2-merged).
// scan_nb: exclusive scan of colsum -> boff (bucket segments of eby).
// bucketB: per-bucket; loads its cntmat column, scans it in LDS, gathers its
//          edges via coalesced destination-indexed reads + LDS binary search,
//          computes per-node off/dinv, scatters eby within an L2-local window.

__global__ void sortA(const int* __restrict__ src, const int* __restrict__ dst,
                      int* __restrict__ ebuf, int* __restrict__ cntmat,
                      int* __restrict__ colsum, int E, int NB) {
    __shared__ int hist[NBMAX];   // counts -> cursors
    __shared__ int ps[256];
    int t = threadIdx.x, k = blockIdx.x;
    int e0 = k * CHA;
    int len = E - e0; if (len > CHA) len = CHA;
    for (int i = t; i < NB; i += 256) hist[i] = 0;
    __syncthreads();
    for (int i = t; i < len; i += 256)
        atomicAdd(&hist[dst[e0 + i] >> BKT_SHIFT], 1);
    __syncthreads();
    // exclusive scan of hist; write packed base|count<<16; hist becomes cursor
    int chunk = (NB + 255) >> 8;
    int lo = t * chunk; if (lo > NB) lo = NB;
    int hi = lo + chunk; if (hi > NB) hi = NB;
    int s = 0;
    for (int i = lo; i < hi; ++i) s += hist[i];
    ps[t] = s;
    __syncthreads();
    for (int d = 1; d < 256; d <<= 1) {
        int v = (t >= d) ? ps[t - d] : 0;
        __syncthreads();
        ps[t] += v;
        __syncthreads();
    }
    int base = (t == 0) ? 0 : ps[t - 1];
    for (int i = lo; i < hi; ++i) {
        int c = hist[i];
        cntmat[(size_t)k * NB + i] = base | (c << 16);
        if (c) atomicAdd(&colsum[i], c);
        hist[i] = base;
        base += c;
    }
    __syncthreads();
    // pass 2: scatter directly into this block's own ebuf chunk (8KB window)
    for (int i = t; i < len; i += 256) {
        int e = e0 + i;
        int d = dst[e], b = d >> BKT_SHIFT;
        int r = atomicAdd(&hist[b], 1);
        ebuf[e0 + r] = src[e] | ((d & (BKT_N - 1)) << 17);
    }
}

__global__ void scan_nb(const int* __restrict__ colsum, int* __restrict__ boff,
                        int* __restrict__ off, int NB, int N, int E) {
    __shared__ int ps[256];
    int t = threadIdx.x;
    int chunk = (NB + 255) >> 8;
    int lo = t * chunk; if (lo > NB) lo = NB;
    int hi = lo + chunk; if (hi > NB) hi = NB;
    int s = 0;
    for (int i = lo; i < hi; ++i) s += colsum[i];
    ps[t] = s;
    __syncthreads();
    for (int d = 1; d < 256; d <<= 1) {
        int v = (t >= d) ? ps[t - d] : 0;
        __syncthreads();
        ps[t] += v;
        __syncthreads();
    }
    int base = (t == 0) ? 0 : ps[t - 1];
    for (int i = lo; i < hi; ++i) { boff[i] = base; base += colsum[i]; }
    if (t == 255) { boff[NB] = E; off[N] = E; }
}

__global__ void bucketB(const int* __restrict__ ebuf, const int* __restrict__ cntmat,
                        const int* __restrict__ boff,
                        int* __restrict__ eby, int* __restrict__ off,
                        float* __restrict__ dinv, int N, int NB, int NBLK) {
    __shared__ int colb[NBLKMAX];
    __shared__ int cols[NBLKMAX + 1];
    __shared__ int ps[256];
    __shared__ int seg[BCAP];
    __shared__ int lcnt[BKT_N];
    __shared__ int lcur[BKT_N];
    int b = blockIdx.x, t = threadIdx.x;
    int n0 = b << BKT_SHIFT;
    int s = boff[b];
    int len = boff[b + 1] - s;
    for (int k = t; k < NBLK; k += 256) {
        int v = cntmat[(size_t)k * NB + b];
        colb[k] = v & 0xFFFF;
        cols[k] = v >> 16;          // count (scanned below)
    }
    if (t < BKT_N) lcnt[t] = 0;
    __syncthreads();
    // exclusive scan cols[0..NBLK)
    int chunk = (NBLK + 255) >> 8;
    int lo = t * chunk; if (lo > NBLK) lo = NBLK;
    int hi = lo + chunk; if (hi > NBLK) hi = NBLK;
    int sm = 0;
    for (int i = lo; i < hi; ++i) sm += cols[i];
    ps[t] = sm;
    __syncthreads();
    for (int d = 1; d < 256; d <<= 1) {
        int v = (t >= d) ? ps[t - d] : 0;
        __syncthreads();
        ps[t] += v;
        __syncthreads();
    }
    int base = (t == 0) ? 0 : ps[t - 1];
    for (int i = lo; i < hi; ++i) { int c = cols[i]; cols[i] = base; base += c; }
    if (t == 255) cols[NBLK] = base;
    __syncthreads();
    bool fits = (len <= BCAP);
    for (int i = t; i < len; i += 256) {
        int l = 0, h = NBLK;       // invariant: cols[l] <= i < cols[h]
        while (h - l > 1) { int m = (l + h) >> 1; if (cols[m] <= i) l = m; else h = m; }
        int v = ebuf[l * CHA + colb[l] + (i - cols[l])];
        if (fits) seg[i] = v;
        atomicAdd(&lcnt[v >> 17], 1);
    }
    __syncthreads();
    if (t == 0) {
        int run = s;
        for (int i = 0; i < BKT_N; ++i) { lcur[i] = run; run += lcnt[i]; }
    }
    __syncthreads();
    if (t < BKT_N) {
        int n = n0 + t;
        if (n < N) { off[n] = lcur[t]; dinv[n] = rsqrtf((float)lcnt[t] + 1.0f); }
    }
    __syncthreads();
    if (fits) {
        for (int i = t; i < len; i += 256) {
            int v = seg[i];
            int pos = atomicAdd(&lcur[v >> 17], 1);
            eby[pos] = v & 0x1FFFF;
        }
    } else {
        for (int i = t; i < len; i += 256) {
            int l = 0, h = NBLK;
            while (h - l > 1) { int m = (l + h) >> 1; if (cols[m] <= i) l = m; else h = m; }
            int v = ebuf[l * CHA + colb[l] + (i - cols[l])];
            int pos = atomicAdd(&lcur[v >> 17], 1);
            eby[pos] = v & 0x1FFFF;
        }
    }
}

// ---------------- GEMMs (register-blocked; outputs pre-scaled by dinv[n]) ----------------

// h'[N][32] = (x[N][128] @ W[128][32]) * dinv[n]
__global__ void gemm128_32v(const float* __restrict__ x, const float* __restrict__ W,
                            const float* __restrict__ dinv, float* __restrict__ h, int N) {
    __shared__ float Ws[128 * 32];
    int t = threadIdx.x;
    for (int i = t; i < 128 * 32; i += 256) Ws[i] = W[i];
    __syncthreads();
    int cg = (t & 7) * 4;
    int n0 = blockIdx.x * 128 + (t >> 3) * 4;
    if (n0 >= N) return;
    if (n0 + 4 <= N) {
        const float* xr = x + (size_t)n0 * 128;
        float4 a0 = {0,0,0,0}, a1 = a0, a2 = a0, a3 = a0;
#pragma unroll
        for (int k4 = 0; k4 < 32; ++k4) {
            float4 x0 = *(const float4*)(xr + k4 * 4);
            float4 x1 = *(const float4*)(xr + 128 + k4 * 4);
            float4 x2 = *(const float4*)(xr + 256 + k4 * 4);
            float4 x3 = *(const float4*)(xr + 384 + k4 * 4);
            float4 w0 = *(const float4*)&Ws[(4 * k4 + 0) * 32 + cg];
            float4 w1 = *(const float4*)&Ws[(4 * k4 + 1) * 32 + cg];
            float4 w2 = *(const float4*)&Ws[(4 * k4 + 2) * 32 + cg];
            float4 w3 = *(const float4*)&Ws[(4 * k4 + 3) * 32 + cg];
            fma4(a0, x0.x, w0); fma4(a0, x0.y, w1); fma4(a0, x0.z, w2); fma4(a0, x0.w, w3);
            fma4(a1, x1.x, w0); fma4(a1, x1.y, w1); fma4(a1, x1.z, w2); fma4(a1, x1.w, w3);
            fma4(a2, x2.x, w0); fma4(a2, x2.y, w1); fma4(a2, x2.z, w2); fma4(a2, x2.w, w3);
            fma4(a3, x3.x, w0); fma4(a3, x3.y, w1); fma4(a3, x3.z, w2); fma4(a3, x3.w, w3);
        }
        scl4(a0, dinv[n0]); scl4(a1, dinv[n0 + 1]); scl4(a2, dinv[n0 + 2]); scl4(a3, dinv[n0 + 3]);
        *(float4*)&h[(size_t)(n0 + 0) * 32 + cg] = a0;
        *(float4*)&h[(size_t)(n0 + 1) * 32 + cg] = a1;
        *(float4*)&h[(size_t)(n0 + 2) * 32 + cg] = a2;
        *(float4*)&h[(size_t)(n0 + 3) * 32 + cg] = a3;
    } else {
        for (int nn = 0; nn < 4; ++nn) {
            int n = n0 + nn; if (n >= N) break;
            float4 a = {0,0,0,0};
            for (int k = 0; k < 128; ++k)
                fma4(a, x[(size_t)n * 128 + k], *(const float4*)&Ws[k * 32 + cg]);
            scl4(a, dinv[n]);
            *(float4*)&h[(size_t)n * 32 + cg] = a;
        }
    }
}

// h'[N][32] = (xc[:, colOff:colOff+32] @ W[32][32]) * dinv[n]   (xc row stride XCS)
__global__ void gemm32_32v(const float* __restrict__ xc, int colOff,
                           const float* __restrict__ W, const float* __restrict__ dinv,
                           float* __restrict__ h, int N) {
    __shared__ float Ws[32 * 32];
    int t = threadIdx.x;
    for (int i = t; i < 32 * 32; i += 256) Ws[i] = W[i];
    __syncthreads();
    int cg = (t & 7) * 4;
    int n0 = blockIdx.x * 128 + (t >> 3) * 4;
    if (n0 >= N) return;
    if (n0 + 4 <= N) {
        const float* xr = xc + (size_t)n0 * XCS + colOff;
        float4 a0 = {0,0,0,0}, a1 = a0, a2 = a0, a3 = a0;
#pragma unroll
        for (int k4 = 0; k4 < 8; ++k4) {
            float4 x0 = *(const float4*)(xr + k4 * 4);
            float4 x1 = *(const float4*)(xr + XCS + k4 * 4);
            float4 x2 = *(const float4*)(xr + 2 * XCS + k4 * 4);
            float4 x3 = *(const float4*)(xr + 3 * XCS + k4 * 4);
            float4 w0 = *(const float4*)&Ws[(4 * k4 + 0) * 32 + cg];
            float4 w1 = *(const float4*)&Ws[(4 * k4 + 1) * 32 + cg];
            float4 w2 = *(const float4*)&Ws[(4 * k4 + 2) * 32 + cg];
            float4 w3 = *(const float4*)&Ws[(4 * k4 + 3) * 32 + cg];
            fma4(a0, x0.x, w0); fma4(a0, x0.y, w1); fma4(a0, x0.z, w2); fma4(a0, x0.w, w3);
            fma4(a1, x1.x, w0); fma4(a1, x1.y, w1); fma4(a1, x1.z, w2); fma4(a1, x1.w, w3);
            fma4(a2, x2.x, w0); fma4(a2, x2.y, w1); fma4(a2, x2.z, w2); fma4(a2, x2.w, w3);
            fma4(a3, x3.x, w0); fma4(a3, x3.y, w1); fma4(a3, x3.z, w2); fma4(a3, x3.w, w3);
        }
        scl4(a0, dinv[n0]); scl4(a1, dinv[n0 + 1]); scl4(a2, dinv[n0 + 2]); scl4(a3, dinv[n0 + 3]);
        *(float4*)&h[(size_t)(n0 + 0) * 32 + cg] = a0;
        *(float4*)&h[(size_t)(n0 + 1) * 32 + cg] = a1;
        *(float4*)&h[(size_t)(n0 + 2) * 32 + cg] = a2;
        *(float4*)&h[(size_t)(n0 + 3) * 32 + cg] = a3;
    } else {
        for (int nn = 0; nn < 4; ++nn) {
            int n = n0 + nn; if (n >= N) break;
            float4 a = {0,0,0,0};
            for (int k = 0; k < 32; ++k)
                fma4(a, xc[(size_t)n * XCS + colOff + k], *(const float4*)&Ws[k * 32 + cg]);
            scl4(a, dinv[n]);
            *(float4*)&h[(size_t)n * 32 + cg] = a;
        }
    }
}

// hv'[N] = (xc[:, colOff:colOff+32] @ W4[32]) * dinv[n]
__global__ void gemm32_1(const float* __restrict__ xc, int colOff,
                         const float* __restrict__ W4, const float* __restrict__ dinv,
                         float* __restrict__ hv, int N) {
    __shared__ float W4s[32];
    int t = threadIdx.x;
    if (t < 32) W4s[t] = W4[t];
    __syncthreads();
    int n = blockIdx.x * 256 + t;
    if (n >= N) return;
    const float* xr = xc + (size_t)n * XCS + colOff;
    float a = 0.f;
#pragma unroll
    for (int k4 = 0; k4 < 8; ++k4) {
        float4 xv = *(const float4*)(xr + k4 * 4);
        a += xv.x * W4s[4 * k4] + xv.y * W4s[4 * k4 + 1]
           + xv.z * W4s[4 * k4 + 2] + xv.w * W4s[4 * k4 + 3];
    }
    hv[n] = a * dinv[n];
}

// ---------------- aggregation (gather, float4, 8 lanes per node) ----------------
// h is pre-scaled by dinv: out = tanh(dn * (h'[n] + sum h'[s]) + b)

__global__ void agg32v(const float* __restrict__ h, const int* __restrict__ off,
                       const int* __restrict__ eby, const float* __restrict__ dinv,
                       const float* __restrict__ b, float* __restrict__ xc, int colOff, int N) {
    int idx = blockIdx.x * 256 + threadIdx.x;
    int n = idx >> 3, q = idx & 7;       // q: which float4 of the 32-ch row
    if (n >= N) return;
    const float4* h4 = (const float4*)h;
    float dn = dinv[n];
    float4 acc = h4[(size_t)n * 8 + q];
    int e0 = off[n], e1 = off[n + 1];
    for (int j = e0; j < e1; ++j) {
        int s = eby[j];
        float4 hs = h4[(size_t)s * 8 + q];
        acc.x += hs.x; acc.y += hs.y; acc.z += hs.z; acc.w += hs.w;
    }
    float4 bb = *(const float4*)&b[q * 4];
    float4 o;
    o.x = tanhf(acc.x * dn + bb.x);
    o.y = tanhf(acc.y * dn + bb.y);
    o.z = tanhf(acc.z * dn + bb.z);
    o.w = tanhf(acc.w * dn + bb.w);
    *(float4*)&xc[(size_t)n * XCS + colOff + q * 4] = o;
}

__global__ void agg1(const float* __restrict__ hv, const int* __restrict__ off,
                     const int* __restrict__ eby, const float* __restrict__ dinv,
                     const float* __restrict__ b4, float* __restrict__ xc, int N) {
    int n = blockIdx.x * 256 + threadIdx.x;
    if (n >= N) return;
    float dn = dinv[n];
    float acc = hv[n];
    int e0 = off[n], e1 = off[n + 1];
    for (int j = e0; j < e1; ++j) acc += hv[eby[j]];
    xc[(size_t)n * XCS + 96] = tanhf(acc * dn + b4[0]);
}

// ---------------- fused head ----------------

__global__ void head_kernel(const float* __restrict__ xc,
                            const float* __restrict__ c5w, const float* __restrict__ c5b,
                            const float* __restrict__ c6w, const float* __restrict__ c6b,
                            const float* __restrict__ f1w, const float* __restrict__ f1b,
                            const float* __restrict__ f2w, const float* __restrict__ f2b,
                            float* __restrict__ out) {
    __shared__ float v[NPG];
    __shared__ int   ord[KK];
    __shared__ float topk[KK * FC];
    __shared__ float o5[16 * 30];
    __shared__ float p5[16 * 15];
    __shared__ float z[352];
    __shared__ float h1[128];
    __shared__ float lg[NC];
    __shared__ float lse;

    int g = blockIdx.x;
    int t = threadIdx.x;
    const float* xg = xc + (size_t)g * NPG * XCS;

    if (t < NPG) v[t] = xg[t * XCS + 96];
    __syncthreads();
    if (t < NPG) {
        float vi = v[t];
        int r = 0;
        for (int j = 0; j < NPG; ++j) {
            float vj = v[j];
            r += (vj > vi) || (vj == vi && j < t);  // stable descending rank
        }
        if (r < KK) ord[r] = t;
    }
    __syncthreads();
    for (int i = t; i < KK * FC; i += 128) {
        int r = i / FC, f = i - r * FC;
        topk[i] = xg[ord[r] * XCS + f];
    }
    __syncthreads();
    for (int i = t; i < 16 * 30; i += 128) {
        int ch = i / 30, tt = i - ch * 30;
        float a = c5b[ch];
        const float* w = c5w + ch * FC;
        const float* xx = topk + tt * FC;
        for (int f = 0; f < FC; ++f) a += xx[f] * w[f];
        o5[ch * 30 + tt] = fmaxf(a, 0.f);
    }
    __syncthreads();
    for (int i = t; i < 16 * 15; i += 128) {
        int ch = i / 15, tt = i - ch * 15;
        p5[i] = fmaxf(o5[ch * 30 + 2 * tt], o5[ch * 30 + 2 * tt + 1]);
    }
    __syncthreads();
    for (int i = t; i < 32 * 11; i += 128) {
        int oc = i / 11, tt = i - oc * 11;
        float a = c6b[oc];
#pragma unroll
        for (int ic = 0; ic < 16; ++ic) {
#pragma unroll
            for (int k = 0; k < 5; ++k)
                a += p5[ic * 15 + tt + k] * c6w[oc * 80 + ic * 5 + k];
        }
        z[oc * 11 + tt] = fmaxf(a, 0.f);
    }
    __syncthreads();
    {
        float a = f1b[t];
        for (int i = 0; i < 352; ++i) a += z[i] * f1w[i * 128 + t];
        h1[t] = fmaxf(a, 0.f);
    }
    __syncthreads();
    if (t < NC) {
        float a = f2b[t];
#pragma unroll
        for (int j = 0; j < 128; ++j) a += h1[j] * f2w[j * NC + t];
        lg[t] = a;
    }
    __syncthreads();
    if (t == 0) {
        float m = lg[0];
        for (int c = 1; c < NC; ++c) m = fmaxf(m, lg[c]);
        float s = 0.f;
        for (int c = 0; c < NC; ++c) s += expf(lg[c] - m);
        lse = m + logf(s);
    }
    __syncthreads();
    if (t < NC) out[(size_t)g * NC + t] = lg[t] - lse;
}

// ---------------- launch ----------------

static inline size_t align_up(size_t x, size_t a) { return (x + a - 1) & ~(a - 1); }

extern "C" void kernel_launch(void* const* d_in, const int* in_sizes, int n_in,
                              void* d_out, int out_size, void* d_ws, size_t ws_size,
                              hipStream_t stream) {
    const float* x   = (const float*)d_in[0];
    const int*   ei  = (const int*)d_in[1];
    const float* W1  = (const float*)d_in[3];
    const float* b1  = (const float*)d_in[4];
    const float* W2  = (const float*)d_in[5];
    const float* b2  = (const float*)d_in[6];
    const float* W3  = (const float*)d_in[7];
    const float* b3  = (const float*)d_in[8];
    const float* W4  = (const float*)d_in[9];
    const float* b4  = (const float*)d_in[10];
    const float* c5w = (const float*)d_in[11];
    const float* c5b = (const float*)d_in[12];
    const float* c6w = (const float*)d_in[13];
    const float* c6b = (const float*)d_in[14];
    const float* f1w = (const float*)d_in[15];
    const float* f1b = (const float*)d_in[16];
    const float* f2w = (const float*)d_in[17];
    const float* f2b = (const float*)d_in[18];
    float* out = (float*)d_out;

    const int N = in_sizes[0] / FIN;
    const int E = in_sizes[1] / 2;
    const int G = N / NPG;
    const int NB = (N + BKT_N - 1) >> BKT_SHIFT;  // buckets of 64 nodes
    const int NBLK = (E + CHA - 1) / CHA;         // sort blocks
    const int* src = ei;
    const int* dst = ei + E;

    char* ws = (char*)d_ws;
    size_t o = 0;
    int*   cntmat = (int*)(ws + o); o = align_up(o + (size_t)NBLK * NB * 4, 256);
    int*   colsum = (int*)(ws + o); o = align_up(o + (size_t)NB * 4, 256);
    int*   boff   = (int*)(ws + o); o = align_up(o + (size_t)(NB + 1) * 4, 256);
    float* dinv   = (float*)(ws + o); o = align_up(o + (size_t)N * 4, 256);
    int*   off    = (int*)(ws + o); o = align_up(o + (size_t)(N + 1) * 4, 256);
    size_t big = (size_t)(E > N * 32 ? E : N * 32);
    int*   ebuf   = (int*)(ws + o); float* h = (float*)(ws + o);  // union: ebuf dead before h live
    o = align_up(o + big * 4, 256);
    int*   eby    = (int*)(ws + o); o = align_up(o + (size_t)E * 4, 256);
    float* xcb    = (float*)(ws + o); o = align_up(o + (size_t)N * XCS * 4, 256);
    (void)ws_size;

    hipMemsetAsync(colsum, 0, (size_t)NB * 4, stream);

    int gbN  = (N + 255) / 256;
    int gbN8 = ((size_t)N * 8 + 255) / 256;
    int gbN128 = (N + 127) / 128;

    sortA<<<NBLK, 256, 0, stream>>>(src, dst, ebuf, cntmat, colsum, E, NB);
    scan_nb<<<1, 256, 0, stream>>>(colsum, boff, off, NB, N, E);
    bucketB<<<NB, 256, 0, stream>>>(ebuf, cntmat, boff, eby, off, dinv, N, NB, NBLK);

    // layer 1: 128 -> 32
    gemm128_32v<<<gbN128, 256, 0, stream>>>(x, W1, dinv, h, N);
    agg32v<<<gbN8, 256, 0, stream>>>(h, off, eby, dinv, b1, xcb, 0, N);
    // layer 2: 32 -> 32
    gemm32_32v<<<gbN128, 256, 0, stream>>>(xcb, 0, W2, dinv, h, N);
    agg32v<<<gbN8, 256, 0, stream>>>(h, off, eby, dinv, b2, xcb, 32, N);
    // layer 3: 32 -> 32
    gemm32_32v<<<gbN128, 256, 0, stream>>>(xcb, 32, W3, dinv, h, N);
    agg32v<<<gbN8, 256, 0, stream>>>(h, off, eby, dinv, b3, xcb, 64, N);
    // layer 4: 32 -> 1
    gemm32_1<<<gbN, 256, 0, stream>>>(xcb, 64, W4, dinv, h, N);
    agg1<<<gbN, 256, 0, stream>>>(h, off, eby, dinv, b4, xcb, N);

    // head
    head_kernel<<<G, 128, 0, stream>>>(xcb, c5w, c5b, c6w, c6b, f1w, f1b, f2w, f2b, out);
}

// Round 8
// 531.960 us; speedup vs baseline: 1.1082x; 1.1082x over previous
//
#include <hip/hip_runtime.h>
#include <hip/hip_bf16.h>
#include <math.h>

// Problem constants (structure of the model; N/E derived at runtime)
#define NPG   100
#define FIN   128
#define KK    30
#define NC    10
#define FC    97    // concat feature width: 32+32+32+1
#define XCS   100   // padded row stride for the concat buffer (16B-aligned rows)

#define BKT_SHIFT 6          // 64 nodes per bucket
#define BKT_N     64
#define NBMAX     2048       // supports N up to 131072 (also the src-packing limit 2^17)
#define CHA       2048       // edges per block in sort pass A
#define NBLKMAX   2048       // supports E up to 2048*2048 = 4.19M
#define BCAP      2560       // LDS-cached edges per bucket in pass B (mean 2048, +11 sigma)

__device__ inline void fma4(float4& a, float s, const float4& w) {
    a.x += s * w.x; a.y += s * w.y; a.z += s * w.z; a.w += s * w.w;
}
__device__ inline void scl4(float4& a, float s) { a.x *= s; a.y *= s; a.z *= s; a.w *= s; }
__device__ inline void add4(float4& a, const float4& b) { a.x += b.x; a.y += b.y; a.z += b.z; a.w += b.w; }

// ---------------- CSR build: transpose bucket sort ----------------
// sortA: per-block counting sort by 64-node bucket (LDS staged, int4 loads),
//        coalesced writeback to the block's own ebuf chunk; emits packed
//        (local_base | count<<16) row into cntmat[k][b]; accumulates colsum.
// transp: tiled transpose cntmat[k][b] -> cntmatT[b][k] (coalesced both ways).
// scan_nb: exclusive scan of colsum -> boff.
// bucketB: per-bucket; reads its cntmatT row coalesced, scans counts in LDS,
//          gathers its edges via destination-indexed reads + binary search,
//          computes per-node off/dinv, scatters eby within an L2-local window.

__global__ void sortA(const int* __restrict__ src, const int* __restrict__ dst,
                      int* __restrict__ ebuf, int* __restrict__ cntmat,
                      int* __restrict__ colsum, int E, int NB) {
    __shared__ int hist[NBMAX];                 // counts -> cursors
    __shared__ __align__(16) int seg[CHA];
    __shared__ int ps[256];
    int t = threadIdx.x, k = blockIdx.x;
    int e0 = k * CHA;
    int len = E - e0; if (len > CHA) len = CHA;
    int len4 = len >> 2;
    const int4* dst4 = (const int4*)(dst + e0);
    const int4* src4 = (const int4*)(src + e0);
    for (int i = t; i < NB; i += 256) hist[i] = 0;
    __syncthreads();
    // pass 1: histogram (int4 loads)
    for (int i = t; i < len4; i += 256) {
        int4 d = dst4[i];
        atomicAdd(&hist[d.x >> BKT_SHIFT], 1);
        atomicAdd(&hist[d.y >> BKT_SHIFT], 1);
        atomicAdd(&hist[d.z >> BKT_SHIFT], 1);
        atomicAdd(&hist[d.w >> BKT_SHIFT], 1);
    }
    for (int i = (len4 << 2) + t; i < len; i += 256)
        atomicAdd(&hist[dst[e0 + i] >> BKT_SHIFT], 1);
    __syncthreads();
    // exclusive scan of hist; write packed base|count<<16; hist becomes cursor
    int chunk = (NB + 255) >> 8;
    int lo = t * chunk; if (lo > NB) lo = NB;
    int hi = lo + chunk; if (hi > NB) hi = NB;
    int s = 0;
    for (int i = lo; i < hi; ++i) s += hist[i];
    ps[t] = s;
    __syncthreads();
    for (int d = 1; d < 256; d <<= 1) {
        int v = (t >= d) ? ps[t - d] : 0;
        __syncthreads();
        ps[t] += v;
        __syncthreads();
    }
    int base = (t == 0) ? 0 : ps[t - 1];
    for (int i = lo; i < hi; ++i) {
        int c = hist[i];
        cntmat[(size_t)k * NB + i] = base | (c << 16);
        if (c) atomicAdd(&colsum[i], c);
        hist[i] = base;
        base += c;
    }
    __syncthreads();
    // pass 2: scatter into LDS seg (int4 loads), then coalesced writeback
    for (int i = t; i < len4; i += 256) {
        int4 d = dst4[i];
        int4 sv = src4[i];
        int r0 = atomicAdd(&hist[d.x >> BKT_SHIFT], 1); seg[r0] = sv.x | ((d.x & (BKT_N - 1)) << 17);
        int r1 = atomicAdd(&hist[d.y >> BKT_SHIFT], 1); seg[r1] = sv.y | ((d.y & (BKT_N - 1)) << 17);
        int r2 = atomicAdd(&hist[d.z >> BKT_SHIFT], 1); seg[r2] = sv.z | ((d.z & (BKT_N - 1)) << 17);
        int r3 = atomicAdd(&hist[d.w >> BKT_SHIFT], 1); seg[r3] = sv.w | ((d.w & (BKT_N - 1)) << 17);
    }
    for (int i = (len4 << 2) + t; i < len; i += 256) {
        int e = e0 + i;
        int d = dst[e];
        int r = atomicAdd(&hist[d >> BKT_SHIFT], 1);
        seg[r] = src[e] | ((d & (BKT_N - 1)) << 17);
    }
    __syncthreads();
    int4* eb4 = (int4*)(ebuf + e0);
    for (int i = t; i < len4; i += 256) eb4[i] = ((const int4*)seg)[i];
    for (int i = (len4 << 2) + t; i < len; i += 256) ebuf[e0 + i] = seg[i];
}

#define TT 32
__global__ void transp(const int* __restrict__ A, int* __restrict__ B, int R, int C) {
    // A[R][C] -> B[C][R]; 256 threads = 32x8
    __shared__ int tile[TT][TT + 1];
    int c0 = blockIdx.x * TT, r0 = blockIdx.y * TT;
    int tx = threadIdx.x & 31, ty = threadIdx.x >> 5;
    for (int dy = ty; dy < TT; dy += 8) {
        int r = r0 + dy, c = c0 + tx;
        tile[dy][tx] = (r < R && c < C) ? A[(size_t)r * C + c] : 0;
    }
    __syncthreads();
    for (int dy = ty; dy < TT; dy += 8) {
        int c = c0 + dy, r = r0 + tx;
        if (c < C && r < R) B[(size_t)c * R + r] = tile[tx][dy];
    }
}

__global__ void scan_nb(const int* __restrict__ colsum, int* __restrict__ boff,
                        int* __restrict__ off, int NB, int N, int E) {
    __shared__ int ps[256];
    int t = threadIdx.x;
    int chunk = (NB + 255) >> 8;
    int lo = t * chunk; if (lo > NB) lo = NB;
    int hi = lo + chunk; if (hi > NB) hi = NB;
    int s = 0;
    for (int i = lo; i < hi; ++i) s += colsum[i];
    ps[t] = s;
    __syncthreads();
    for (int d = 1; d < 256; d <<= 1) {
        int v = (t >= d) ? ps[t - d] : 0;
        __syncthreads();
        ps[t] += v;
        __syncthreads();
    }
    int base = (t == 0) ? 0 : ps[t - 1];
    for (int i = lo; i < hi; ++i) { boff[i] = base; base += colsum[i]; }
    if (t == 255) { boff[NB] = E; off[N] = E; }
}

__global__ void bucketB(const int* __restrict__ ebuf, const int* __restrict__ cntmatT,
                        const int* __restrict__ boff,
                        int* __restrict__ eby, int* __restrict__ off,
                        float* __restrict__ dinv, int N, int NB, int NBLK) {
    __shared__ int cc[NBLKMAX];      // after rescan: base | scanned_offset<<16
    __shared__ int ps[256];
    __shared__ int seg[BCAP];
    __shared__ int lcnt[BKT_N];
    __shared__ int lcur[BKT_N];
    int b = blockIdx.x, t = threadIdx.x;
    int n0 = b << BKT_SHIFT;
    int s = boff[b];
    int len = boff[b + 1] - s;
    for (int k = t; k < NBLK; k += 256) cc[k] = cntmatT[(size_t)b * NBLK + k];
    if (t < BKT_N) lcnt[t] = 0;
    __syncthreads();
    // exclusive scan of counts (cc>>16), repack scanned offset into high 16
    int chunk = (NBLK + 255) >> 8;
    int lo = t * chunk; if (lo > NBLK) lo = NBLK;
    int hi = lo + chunk; if (hi > NBLK) hi = NBLK;
    int sm = 0;
    for (int i = lo; i < hi; ++i) sm += (cc[i] >> 16) & 0xFFFF;
    ps[t] = sm;
    __syncthreads();
    for (int d = 1; d < 256; d <<= 1) {
        int v = (t >= d) ? ps[t - d] : 0;
        __syncthreads();
        ps[t] += v;
        __syncthreads();
    }
    int base = (t == 0) ? 0 : ps[t - 1];
    for (int i = lo; i < hi; ++i) {
        int c = (cc[i] >> 16) & 0xFFFF;
        cc[i] = (cc[i] & 0xFFFF) | (base << 16);
        base += c;
    }
    __syncthreads();
    bool fits = (len <= BCAP);
    for (int i = t; i < len; i += 256) {
        int l = 0, h = NBLK;        // invariant: colOff(l) <= i < colOff(h)
        while (h - l > 1) { int m = (l + h) >> 1; if ((cc[m] >> 16) <= i) l = m; else h = m; }
        int v = ebuf[l * CHA + (cc[l] & 0xFFFF) + (i - (cc[l] >> 16))];
        if (fits) seg[i] = v;
        atomicAdd(&lcnt[v >> 17], 1);
    }
    __syncthreads();
    if (t == 0) {
        int run = s;
        for (int i = 0; i < BKT_N; ++i) { lcur[i] = run; run += lcnt[i]; }
    }
    __syncthreads();
    if (t < BKT_N) {
        int n = n0 + t;
        if (n < N) { off[n] = lcur[t]; dinv[n] = rsqrtf((float)lcnt[t] + 1.0f); }
    }
    __syncthreads();
    if (fits) {
        for (int i = t; i < len; i += 256) {
            int v = seg[i];
            int pos = atomicAdd(&lcur[v >> 17], 1);
            eby[pos] = v & 0x1FFFF;
        }
    } else {
        for (int i = t; i < len; i += 256) {
            int l = 0, h = NBLK;
            while (h - l > 1) { int m = (l + h) >> 1; if ((cc[m] >> 16) <= i) l = m; else h = m; }
            int v = ebuf[l * CHA + (cc[l] & 0xFFFF) + (i - (cc[l] >> 16))];
            int pos = atomicAdd(&lcur[v >> 17], 1);
            eby[pos] = v & 0x1FFFF;
        }
    }
}

// ---------------- GEMMs (register-blocked; outputs pre-scaled by dinv[n]) ----------------

// h'[N][32] = (x[N][128] @ W[128][32]) * dinv[n]
__global__ void gemm128_32v(const float* __restrict__ x, const float* __restrict__ W,
                            const float* __restrict__ dinv, float* __restrict__ h, int N) {
    __shared__ float Ws[128 * 32];
    int t = threadIdx.x;
    for (int i = t; i < 128 * 32; i += 256) Ws[i] = W[i];
    __syncthreads();
    int cg = (t & 7) * 4;
    int n0 = blockIdx.x * 128 + (t >> 3) * 4;
    if (n0 >= N) return;
    if (n0 + 4 <= N) {
        const float* xr = x + (size_t)n0 * 128;
        float4 a0 = {0,0,0,0}, a1 = a0, a2 = a0, a3 = a0;
#pragma unroll
        for (int k4 = 0; k4 < 32; ++k4) {
            float4 x0 = *(const float4*)(xr + k4 * 4);
            float4 x1 = *(const float4*)(xr + 128 + k4 * 4);
            float4 x2 = *(const float4*)(xr + 256 + k4 * 4);
            float4 x3 = *(const float4*)(xr + 384 + k4 * 4);
            float4 w0 = *(const float4*)&Ws[(4 * k4 + 0) * 32 + cg];
            float4 w1 = *(const float4*)&Ws[(4 * k4 + 1) * 32 + cg];
            float4 w2 = *(const float4*)&Ws[(4 * k4 + 2) * 32 + cg];
            float4 w3 = *(const float4*)&Ws[(4 * k4 + 3) * 32 + cg];
            fma4(a0, x0.x, w0); fma4(a0, x0.y, w1); fma4(a0, x0.z, w2); fma4(a0, x0.w, w3);
            fma4(a1, x1.x, w0); fma4(a1, x1.y, w1); fma4(a1, x1.z, w2); fma4(a1, x1.w, w3);
            fma4(a2, x2.x, w0); fma4(a2, x2.y, w1); fma4(a2, x2.z, w2); fma4(a2, x2.w, w3);
            fma4(a3, x3.x, w0); fma4(a3, x3.y, w1); fma4(a3, x3.z, w2); fma4(a3, x3.w, w3);
        }
        scl4(a0, dinv[n0]); scl4(a1, dinv[n0 + 1]); scl4(a2, dinv[n0 + 2]); scl4(a3, dinv[n0 + 3]);
        *(float4*)&h[(size_t)(n0 + 0) * 32 + cg] = a0;
        *(float4*)&h[(size_t)(n0 + 1) * 32 + cg] = a1;
        *(float4*)&h[(size_t)(n0 + 2) * 32 + cg] = a2;
        *(float4*)&h[(size_t)(n0 + 3) * 32 + cg] = a3;
    } else {
        for (int nn = 0; nn < 4; ++nn) {
            int n = n0 + nn; if (n >= N) break;
            float4 a = {0,0,0,0};
            for (int k = 0; k < 128; ++k)
                fma4(a, x[(size_t)n * 128 + k], *(const float4*)&Ws[k * 32 + cg]);
            scl4(a, dinv[n]);
            *(float4*)&h[(size_t)n * 32 + cg] = a;
        }
    }
}

// h'[N][32] = (xc[:, colOff:colOff+32] @ W[32][32]) * dinv[n]   (xc row stride XCS)
__global__ void gemm32_32v(const float* __restrict__ xc, int colOff,
                           const float* __restrict__ W, const float* __restrict__ dinv,
                           float* __restrict__ h, int N) {
    __shared__ float Ws[32 * 32];
    int t = threadIdx.x;
    for (int i = t; i < 32 * 32; i += 256) Ws[i] = W[i];
    __syncthreads();
    int cg = (t & 7) * 4;
    int n0 = blockIdx.x * 128 + (t >> 3) * 4;
    if (n0 >= N) return;
    if (n0 + 4 <= N) {
        const float* xr = xc + (size_t)n0 * XCS + colOff;
        float4 a0 = {0,0,0,0}, a1 = a0, a2 = a0, a3 = a0;
#pragma unroll
        for (int k4 = 0; k4 < 8; ++k4) {
            float4 x0 = *(const float4*)(xr + k4 * 4);
            float4 x1 = *(const float4*)(xr + XCS + k4 * 4);
            float4 x2 = *(const float4*)(xr + 2 * XCS + k4 * 4);
            float4 x3 = *(const float4*)(xr + 3 * XCS + k4 * 4);
            float4 w0 = *(const float4*)&Ws[(4 * k4 + 0) * 32 + cg];
            float4 w1 = *(const float4*)&Ws[(4 * k4 + 1) * 32 + cg];
            float4 w2 = *(const float4*)&Ws[(4 * k4 + 2) * 32 + cg];
            float4 w3 = *(const float4*)&Ws[(4 * k4 + 3) * 32 + cg];
            fma4(a0, x0.x, w0); fma4(a0, x0.y, w1); fma4(a0, x0.z, w2); fma4(a0, x0.w, w3);
            fma4(a1, x1.x, w0); fma4(a1, x1.y, w1); fma4(a1, x1.z, w2); fma4(a1, x1.w, w3);
            fma4(a2, x2.x, w0); fma4(a2, x2.y, w1); fma4(a2, x2.z, w2); fma4(a2, x2.w, w3);
            fma4(a3, x3.x, w0); fma4(a3, x3.y, w1); fma4(a3, x3.z, w2); fma4(a3, x3.w, w3);
        }
        scl4(a0, dinv[n0]); scl4(a1, dinv[n0 + 1]); scl4(a2, dinv[n0 + 2]); scl4(a3, dinv[n0 + 3]);
        *(float4*)&h[(size_t)(n0 + 0) * 32 + cg] = a0;
        *(float4*)&h[(size_t)(n0 + 1) * 32 + cg] = a1;
        *(float4*)&h[(size_t)(n0 + 2) * 32 + cg] = a2;
        *(float4*)&h[(size_t)(n0 + 3) * 32 + cg] = a3;
    } else {
        for (int nn = 0; nn < 4; ++nn) {
            int n = n0 + nn; if (n >= N) break;
            float4 a = {0,0,0,0};
            for (int k = 0; k < 32; ++k)
                fma4(a, xc[(size_t)n * XCS + colOff + k], *(const float4*)&Ws[k * 32 + cg]);
            scl4(a, dinv[n]);
            *(float4*)&h[(size_t)n * 32 + cg] = a;
        }
    }
}

// hv'[N] = (xc[:, colOff:colOff+32] @ W4[32]) * dinv[n]
__global__ void gemm32_1(const float* __restrict__ xc, int colOff,
                         const float* __restrict__ W4, const float* __restrict__ dinv,
                         float* __restrict__ hv, int N) {
    __shared__ float W4s[32];
    int t = threadIdx.x;
    if (t < 32) W4s[t] = W4[t];
    __syncthreads();
    int n = blockIdx.x * 256 + t;
    if (n >= N) return;
    const float* xr = xc + (size_t)n * XCS + colOff;
    float a = 0.f;
#pragma unroll
    for (int k4 = 0; k4 < 8; ++k4) {
        float4 xv = *(const float4*)(xr + k4 * 4);
        a += xv.x * W4s[4 * k4] + xv.y * W4s[4 * k4 + 1]
           + xv.z * W4s[4 * k4 + 2] + xv.w * W4s[4 * k4 + 3];
    }
    hv[n] = a * dinv[n];
}

// ---------------- aggregation (gather, float4, 8 lanes per node) ----------------
// h is pre-scaled by dinv: out = tanh(dn * (h'[n] + sum h'[s]) + b)

__global__ void agg32v(const float* __restrict__ h, const int* __restrict__ off,
                       const int* __restrict__ eby, const float* __restrict__ dinv,
                       const float* __restrict__ b, float* __restrict__ xc, int colOff, int N) {
    int idx = blockIdx.x * 256 + threadIdx.x;
    int n = idx >> 3, q = idx & 7;       // q: which float4 of the 32-ch row
    if (n >= N) return;
    const float4* h4 = (const float4*)h;
    float dn = dinv[n];
    float4 acc = h4[(size_t)n * 8 + q];
    float4 acc2 = {0, 0, 0, 0};
    int e0 = off[n], e1 = off[n + 1];
    int j = e0;
    for (; j + 1 < e1; j += 2) {
        int s0 = eby[j], s1 = eby[j + 1];
        float4 h0 = h4[(size_t)s0 * 8 + q];
        float4 h1 = h4[(size_t)s1 * 8 + q];
        add4(acc, h0); add4(acc2, h1);
    }
    if (j < e1) add4(acc, h4[(size_t)eby[j] * 8 + q]);
    add4(acc, acc2);
    float4 bb = *(const float4*)&b[q * 4];
    float4 o;
    o.x = tanhf(acc.x * dn + bb.x);
    o.y = tanhf(acc.y * dn + bb.y);
    o.z = tanhf(acc.z * dn + bb.z);
    o.w = tanhf(acc.w * dn + bb.w);
    *(float4*)&xc[(size_t)n * XCS + colOff + q * 4] = o;
}

__global__ void agg1(const float* __restrict__ hv, const int* __restrict__ off,
                     const int* __restrict__ eby, const float* __restrict__ dinv,
                     const float* __restrict__ b4, float* __restrict__ xc, int N) {
    int n = blockIdx.x * 256 + threadIdx.x;
    if (n >= N) return;
    float dn = dinv[n];
    float acc = hv[n], acc2 = 0.f;
    int e0 = off[n], e1 = off[n + 1];
    int j = e0;
    for (; j + 1 < e1; j += 2) { acc += hv[eby[j]]; acc2 += hv[eby[j + 1]]; }
    if (j < e1) acc += hv[eby[j]];
    xc[(size_t)n * XCS + 96] = tanhf((acc + acc2) * dn + b4[0]);
}

// ---------------- fused head ----------------

__global__ void head_kernel(const float* __restrict__ xc,
                            const float* __restrict__ c5w, const float* __restrict__ c5b,
                            const float* __restrict__ c6w, const float* __restrict__ c6b,
                            const float* __restrict__ f1w, const float* __restrict__ f1b,
                            const float* __restrict__ f2w, const float* __restrict__ f2b,
                            float* __restrict__ out) {
    __shared__ float v[NPG];
    __shared__ int   ord[KK];
    __shared__ float topk[KK * FC];
    __shared__ float o5[16 * 30];
    __shared__ float p5[16 * 15];
    __shared__ float z[352];
    __shared__ float h1[128];
    __shared__ float lg[NC];
    __shared__ float lse;

    int g = blockIdx.x;
    int t = threadIdx.x;
    const float* xg = xc + (size_t)g * NPG * XCS;

    if (t < NPG) v[t] = xg[t * XCS + 96];
    __syncthreads();
    if (t < NPG) {
        float vi = v[t];
        int r = 0;
        for (int j = 0; j < NPG; ++j) {
            float vj = v[j];
            r += (vj > vi) || (vj == vi && j < t);  // stable descending rank
        }
        if (r < KK) ord[r] = t;
    }
    __syncthreads();
    for (int i = t; i < KK * FC; i += 128) {
        int r = i / FC, f = i - r * FC;
        topk[i] = xg[ord[r] * XCS + f];
    }
    __syncthreads();
    for (int i = t; i < 16 * 30; i += 128) {
        int ch = i / 30, tt = i - ch * 30;
        float a = c5b[ch];
        const float* w = c5w + ch * FC;
        const float* xx = topk + tt * FC;
        for (int f = 0; f < FC; ++f) a += xx[f] * w[f];
        o5[ch * 30 + tt] = fmaxf(a, 0.f);
    }
    __syncthreads();
    for (int i = t; i < 16 * 15; i += 128) {
        int ch = i / 15, tt = i - ch * 15;
        p5[i] = fmaxf(o5[ch * 30 + 2 * tt], o5[ch * 30 + 2 * tt + 1]);
    }
    __syncthreads();
    for (int i = t; i < 32 * 11; i += 128) {
        int oc = i / 11, tt = i - oc * 11;
        float a = c6b[oc];
#pragma unroll
        for (int ic = 0; ic < 16; ++ic) {
#pragma unroll
            for (int k = 0; k < 5; ++k)
                a += p5[ic * 15 + tt + k] * c6w[oc * 80 + ic * 5 + k];
        }
        z[oc * 11 + tt] = fmaxf(a, 0.f);
    }
    __syncthreads();
    {
        float a = f1b[t];
        for (int i = 0; i < 352; ++i) a += z[i] * f1w[i * 128 + t];
        h1[t] = fmaxf(a, 0.f);
    }
    __syncthreads();
    if (t < NC) {
        float a = f2b[t];
#pragma unroll
        for (int j = 0; j < 128; ++j) a += h1[j] * f2w[j * NC + t];
        lg[t] = a;
    }
    __syncthreads();
    if (t == 0) {
        float m = lg[0];
        for (int c = 1; c < NC; ++c) m = fmaxf(m, lg[c]);
        float s = 0.f;
        for (int c = 0; c < NC; ++c) s += expf(lg[c] - m);
        lse = m + logf(s);
    }
    __syncthreads();
    if (t < NC) out[(size_t)g * NC + t] = lg[t] - lse;
}

// ---------------- launch ----------------

static inline size_t align_up(size_t x, size_t a) { return (x + a - 1) & ~(a - 1); }

extern "C" void kernel_launch(void* const* d_in, const int* in_sizes, int n_in,
                              void* d_out, int out_size, void* d_ws, size_t ws_size,
                              hipStream_t stream) {
    const float* x   = (const float*)d_in[0];
    const int*   ei  = (const int*)d_in[1];
    const float* W1  = (const float*)d_in[3];
    const float* b1  = (const float*)d_in[4];
    const float* W2  = (const float*)d_in[5];
    const float* b2  = (const float*)d_in[6];
    const float* W3  = (const float*)d_in[7];
    const float* b3  = (const float*)d_in[8];
    const float* W4  = (const float*)d_in[9];
    const float* b4  = (const float*)d_in[10];
    const float* c5w = (const float*)d_in[11];
    const float* c5b = (const float*)d_in[12];
    const float* c6w = (const float*)d_in[13];
    const float* c6b = (const float*)d_in[14];
    const float* f1w = (const float*)d_in[15];
    const float* f1b = (const float*)d_in[16];
    const float* f2w = (const float*)d_in[17];
    const float* f2b = (const float*)d_in[18];
    float* out = (float*)d_out;

    const int N = in_sizes[0] / FIN;
    const int E = in_sizes[1] / 2;
    const int G = N / NPG;
    const int NB = (N + BKT_N - 1) >> BKT_SHIFT;  // buckets of 64 nodes
    const int NBLK = (E + CHA - 1) / CHA;         // sort blocks
    const int* src = ei;
    const int* dst = ei + E;

    // workspace plan (with lifetime unions):
    //  [colsum][boff][dinv][off][ ebuf | h ][ eby | cntmat ][ xcb | cntmatT ]
    //  cntmat:  written by sortA, read by transp, dead before bucketB writes eby
    //  cntmatT: written by transp, read by bucketB, dead before agg writes xcb
    //  ebuf:    written by sortA, read by bucketB, dead before gemm writes h
    char* ws = (char*)d_ws;
    size_t o = 0;
    int*   colsum = (int*)(ws + o); o = align_up(o + (size_t)NB * 4, 256);
    int*   boff   = (int*)(ws + o); o = align_up(o + (size_t)(NB + 1) * 4, 256);
    float* dinv   = (float*)(ws + o); o = align_up(o + (size_t)N * 4, 256);
    int*   off    = (int*)(ws + o); o = align_up(o + (size_t)(N + 1) * 4, 256);
    size_t big = (size_t)(E > N * 32 ? E : N * 32);
    int*   ebuf   = (int*)(ws + o); float* h = (float*)(ws + o);
    o = align_up(o + big * 4, 256);
    size_t big2 = (size_t)E * 4 > (size_t)NBLK * NB * 4 ? (size_t)E * 4 : (size_t)NBLK * NB * 4;
    int*   eby    = (int*)(ws + o); int* cntmat = (int*)(ws + o);
    o = align_up(o + big2, 256);
    size_t big3 = (size_t)N * XCS * 4 > (size_t)NBLK * NB * 4 ? (size_t)N * XCS * 4 : (size_t)NBLK * NB * 4;
    float* xcb    = (float*)(ws + o); int* cntmatT = (int*)(ws + o);
    o = align_up(o + big3, 256);
    (void)ws_size;

    hipMemsetAsync(colsum, 0, (size_t)NB * 4, stream);

    int gbN  = (N + 255) / 256;
    int gbN8 = ((size_t)N * 8 + 255) / 256;
    int gbN128 = (N + 127) / 128;

    sortA<<<NBLK, 256, 0, stream>>>(src, dst, ebuf, cntmat, colsum, E, NB);
    dim3 tg((NB + TT - 1) / TT, (NBLK + TT - 1) / TT);
    transp<<<tg, 256, 0, stream>>>(cntmat, cntmatT, NBLK, NB);
    scan_nb<<<1, 256, 0, stream>>>(colsum, boff, off, NB, N, E);
    bucketB<<<NB, 256, 0, stream>>>(ebuf, cntmatT, boff, eby, off, dinv, N, NB, NBLK);

    // layer 1: 128 -> 32
    gemm128_32v<<<gbN128, 256, 0, stream>>>(x, W1, dinv, h, N);
    agg32v<<<gbN8, 256, 0, stream>>>(h, off, eby, dinv, b1, xcb, 0, N);
    // layer 2: 32 -> 32
    gemm32_32v<<<gbN128, 256, 0, stream>>>(xcb, 0, W2, dinv, h, N);
    agg32v<<<gbN8, 256, 0, stream>>>(h, off, eby, dinv, b2, xcb, 32, N);
    // layer 3: 32 -> 32
    gemm32_32v<<<gbN128, 256, 0, stream>>>(xcb, 32, W3, dinv, h, N);
    agg32v<<<gbN8, 256, 0, stream>>>(h, off, eby, dinv, b3, xcb, 64, N);
    // layer 4: 32 -> 1
    gemm32_1<<<gbN, 256, 0, stream>>>(xcb, 64, W4, dinv, h, N);
    agg1<<<gbN, 256, 0, stream>>>(h, off, eby, dinv, b4, xcb, N);

    // head
    head_kernel<<<G, 128, 0, stream>>>(xcb, c5w, c5b, c6w, c6b, f1w, f1b, f2w, f2b, out);
}

// Round 9
// 338.117 us; speedup vs baseline: 1.7435x; 1.5733x over previous
//
#include <hip/hip_runtime.h>
#include <hip/hip_bf16.h>
#include <math.h>

// Problem constants (structure of the model; N/E derived at runtime)
#define NPG   100
#define FIN   128
#define KK    30
#define NC    10
#define FC    97    // concat feature width: 32+32+32+1
#define XCS   100   // padded row stride for the concat buffer (16B-aligned rows)

#define BKT_SHIFT 6          // 64 nodes per bucket
#define BKT_N     64
#define NBMAX     2048       // supports N up to 131072 (also the src-packing limit 2^17)
#define CHA       4096       // edges per block in sort pass A
#define NBLKMAX   1024       // supports E up to 1024*4096 = 4.19M
#define BCAP      2560       // LDS-cached edges per bucket in pass B (mean 2048, +11 sigma)

__device__ inline void fma4(float4& a, float s, const float4& w) {
    a.x += s * w.x; a.y += s * w.y; a.z += s * w.z; a.w += s * w.w;
}
__device__ inline void scl4(float4& a, float s) { a.x *= s; a.y *= s; a.z *= s; a.w *= s; }
__device__ inline void add4(float4& a, const float4& b) { a.x += b.x; a.y += b.y; a.z += b.z; a.w += b.w; }

// ---------------- CSR build: transpose bucket sort (NO global atomics) ----------------
// sortA:   per-block counting sort by 64-node bucket (LDS staged, int4 loads),
//          coalesced writeback to the block's own ebuf chunk; emits packed
//          (local_base | count<<16) row into cntmat[k][b].
// transp:  tiled transpose cntmat[k][b] -> cntmatT[b][k] (coalesced both ways).
// colsum_k: per-bucket row reduction of cntmatT counts -> colsum (no atomics).
// scan_nb: exclusive scan of colsum -> boff.
// bucketB: per-bucket; reads its cntmatT row coalesced, scans counts in LDS,
//          gathers its edges via destination-indexed reads + binary search,
//          computes per-node off/dinv, scatters eby within an L2-local window.

__global__ void sortA(const int* __restrict__ src, const int* __restrict__ dst,
                      int* __restrict__ ebuf, int* __restrict__ cntmat,
                      int E, int NB) {
    __shared__ int hist[NBMAX];                 // counts -> cursors
    __shared__ __align__(16) int seg[CHA];
    __shared__ int ps[256];
    int t = threadIdx.x, k = blockIdx.x;
    int e0 = k * CHA;
    int len = E - e0; if (len > CHA) len = CHA;
    int len4 = len >> 2;
    const int4* dst4 = (const int4*)(dst + e0);
    const int4* src4 = (const int4*)(src + e0);
    for (int i = t; i < NB; i += 256) hist[i] = 0;
    __syncthreads();
    // pass 1: histogram (int4 loads)
    for (int i = t; i < len4; i += 256) {
        int4 d = dst4[i];
        atomicAdd(&hist[d.x >> BKT_SHIFT], 1);
        atomicAdd(&hist[d.y >> BKT_SHIFT], 1);
        atomicAdd(&hist[d.z >> BKT_SHIFT], 1);
        atomicAdd(&hist[d.w >> BKT_SHIFT], 1);
    }
    for (int i = (len4 << 2) + t; i < len; i += 256)
        atomicAdd(&hist[dst[e0 + i] >> BKT_SHIFT], 1);
    __syncthreads();
    // exclusive scan of hist; write packed base|count<<16; hist becomes cursor
    int chunk = (NB + 255) >> 8;
    int lo = t * chunk; if (lo > NB) lo = NB;
    int hi = lo + chunk; if (hi > NB) hi = NB;
    int s = 0;
    for (int i = lo; i < hi; ++i) s += hist[i];
    ps[t] = s;
    __syncthreads();
    for (int d = 1; d < 256; d <<= 1) {
        int v = (t >= d) ? ps[t - d] : 0;
        __syncthreads();
        ps[t] += v;
        __syncthreads();
    }
    int base = (t == 0) ? 0 : ps[t - 1];
    for (int i = lo; i < hi; ++i) {
        int c = hist[i];
        cntmat[(size_t)k * NB + i] = base | (c << 16);
        hist[i] = base;
        base += c;
    }
    __syncthreads();
    // pass 2: scatter into LDS seg (int4 loads), then coalesced writeback
    for (int i = t; i < len4; i += 256) {
        int4 d = dst4[i];
        int4 sv = src4[i];
        int r0 = atomicAdd(&hist[d.x >> BKT_SHIFT], 1); seg[r0] = sv.x | ((d.x & (BKT_N - 1)) << 17);
        int r1 = atomicAdd(&hist[d.y >> BKT_SHIFT], 1); seg[r1] = sv.y | ((d.y & (BKT_N - 1)) << 17);
        int r2 = atomicAdd(&hist[d.z >> BKT_SHIFT], 1); seg[r2] = sv.z | ((d.z & (BKT_N - 1)) << 17);
        int r3 = atomicAdd(&hist[d.w >> BKT_SHIFT], 1); seg[r3] = sv.w | ((d.w & (BKT_N - 1)) << 17);
    }
    for (int i = (len4 << 2) + t; i < len; i += 256) {
        int e = e0 + i;
        int d = dst[e];
        int r = atomicAdd(&hist[d >> BKT_SHIFT], 1);
        seg[r] = src[e] | ((d & (BKT_N - 1)) << 17);
    }
    __syncthreads();
    int4* eb4 = (int4*)(ebuf + e0);
    for (int i = t; i < len4; i += 256) eb4[i] = ((const int4*)seg)[i];
    for (int i = (len4 << 2) + t; i < len; i += 256) ebuf[e0 + i] = seg[i];
}

#define TT 32
__global__ void transp(const int* __restrict__ A, int* __restrict__ B, int R, int C) {
    // A[R][C] -> B[C][R]; 256 threads = 32x8
    __shared__ int tile[TT][TT + 1];
    int c0 = blockIdx.x * TT, r0 = blockIdx.y * TT;
    int tx = threadIdx.x & 31, ty = threadIdx.x >> 5;
    for (int dy = ty; dy < TT; dy += 8) {
        int r = r0 + dy, c = c0 + tx;
        tile[dy][tx] = (r < R && c < C) ? A[(size_t)r * C + c] : 0;
    }
    __syncthreads();
    for (int dy = ty; dy < TT; dy += 8) {
        int c = c0 + dy, r = r0 + tx;
        if (c < C && r < R) B[(size_t)c * R + r] = tile[tx][dy];
    }
}

__global__ void colsum_k(const int* __restrict__ cntmatT, int* __restrict__ colsum,
                         int NBLK) {
    __shared__ int red[256];
    int b = blockIdx.x, t = threadIdx.x;
    const int* row = cntmatT + (size_t)b * NBLK;
    int s = 0;
    for (int k = t; k < NBLK; k += 256) s += (row[k] >> 16) & 0xFFFF;
    red[t] = s;
    __syncthreads();
    for (int d = 128; d > 0; d >>= 1) {
        if (t < d) red[t] += red[t + d];
        __syncthreads();
    }
    if (t == 0) colsum[b] = red[0];
}

__global__ void scan_nb(const int* __restrict__ colsum, int* __restrict__ boff,
                        int* __restrict__ off, int NB, int N, int E) {
    __shared__ int ps[256];
    int t = threadIdx.x;
    int chunk = (NB + 255) >> 8;
    int lo = t * chunk; if (lo > NB) lo = NB;
    int hi = lo + chunk; if (hi > NB) hi = NB;
    int s = 0;
    for (int i = lo; i < hi; ++i) s += colsum[i];
    ps[t] = s;
    __syncthreads();
    for (int d = 1; d < 256; d <<= 1) {
        int v = (t >= d) ? ps[t - d] : 0;
        __syncthreads();
        ps[t] += v;
        __syncthreads();
    }
    int base = (t == 0) ? 0 : ps[t - 1];
    for (int i = lo; i < hi; ++i) { boff[i] = base; base += colsum[i]; }
    if (t == 255) { boff[NB] = E; off[N] = E; }
}

__global__ void bucketB(const int* __restrict__ ebuf, const int* __restrict__ cntmatT,
                        const int* __restrict__ boff,
                        int* __restrict__ eby, int* __restrict__ off,
                        float* __restrict__ dinv, int N, int NB, int NBLK) {
    __shared__ int cc[NBLKMAX];      // after rescan: base | scanned_offset<<16
    __shared__ int ps[256];
    __shared__ int seg[BCAP];
    __shared__ int lcnt[BKT_N];
    __shared__ int lcur[BKT_N];
    int b = blockIdx.x, t = threadIdx.x;
    int n0 = b << BKT_SHIFT;
    int s = boff[b];
    int len = boff[b + 1] - s;
    for (int k = t; k < NBLK; k += 256) cc[k] = cntmatT[(size_t)b * NBLK + k];
    if (t < BKT_N) lcnt[t] = 0;
    __syncthreads();
    // exclusive scan of counts (cc>>16), repack scanned offset into high 16
    int chunk = (NBLK + 255) >> 8;
    int lo = t * chunk; if (lo > NBLK) lo = NBLK;
    int hi = lo + chunk; if (hi > NBLK) hi = NBLK;
    int sm = 0;
    for (int i = lo; i < hi; ++i) sm += (cc[i] >> 16) & 0xFFFF;
    ps[t] = sm;
    __syncthreads();
    for (int d = 1; d < 256; d <<= 1) {
        int v = (t >= d) ? ps[t - d] : 0;
        __syncthreads();
        ps[t] += v;
        __syncthreads();
    }
    int base = (t == 0) ? 0 : ps[t - 1];
    for (int i = lo; i < hi; ++i) {
        int c = (cc[i] >> 16) & 0xFFFF;
        cc[i] = (cc[i] & 0xFFFF) | (base << 16);
        base += c;
    }
    __syncthreads();
    bool fits = (len <= BCAP);
    for (int i = t; i < len; i += 256) {
        int l = 0, h = NBLK;        // invariant: colOff(l) <= i < colOff(h)
        while (h - l > 1) { int m = (l + h) >> 1; if ((cc[m] >> 16) <= i) l = m; else h = m; }
        int v = ebuf[l * CHA + (cc[l] & 0xFFFF) + (i - (cc[l] >> 16))];
        if (fits) seg[i] = v;
        atomicAdd(&lcnt[v >> 17], 1);
    }
    __syncthreads();
    if (t == 0) {
        int run = s;
        for (int i = 0; i < BKT_N; ++i) { lcur[i] = run; run += lcnt[i]; }
    }
    __syncthreads();
    if (t < BKT_N) {
        int n = n0 + t;
        if (n < N) { off[n] = lcur[t]; dinv[n] = rsqrtf((float)lcnt[t] + 1.0f); }
    }
    __syncthreads();
    if (fits) {
        for (int i = t; i < len; i += 256) {
            int v = seg[i];
            int pos = atomicAdd(&lcur[v >> 17], 1);
            eby[pos] = v & 0x1FFFF;
        }
    } else {
        for (int i = t; i < len; i += 256) {
            int l = 0, h = NBLK;
            while (h - l > 1) { int m = (l + h) >> 1; if ((cc[m] >> 16) <= i) l = m; else h = m; }
            int v = ebuf[l * CHA + (cc[l] & 0xFFFF) + (i - (cc[l] >> 16))];
            int pos = atomicAdd(&lcur[v >> 17], 1);
            eby[pos] = v & 0x1FFFF;
        }
    }
}

// ---------------- GEMMs (register-blocked; outputs pre-scaled by dinv[n]) ----------------

// h'[N][32] = (x[N][128] @ W[128][32]) * dinv[n]
__global__ void gemm128_32v(const float* __restrict__ x, const float* __restrict__ W,
                            const float* __restrict__ dinv, float* __restrict__ h, int N) {
    __shared__ float Ws[128 * 32];
    int t = threadIdx.x;
    for (int i = t; i < 128 * 32; i += 256) Ws[i] = W[i];
    __syncthreads();
    int cg = (t & 7) * 4;
    int n0 = blockIdx.x * 128 + (t >> 3) * 4;
    if (n0 >= N) return;
    if (n0 + 4 <= N) {
        const float* xr = x + (size_t)n0 * 128;
        float4 a0 = {0,0,0,0}, a1 = a0, a2 = a0, a3 = a0;
#pragma unroll
        for (int k4 = 0; k4 < 32; ++k4) {
            float4 x0 = *(const float4*)(xr + k4 * 4);
            float4 x1 = *(const float4*)(xr + 128 + k4 * 4);
            float4 x2 = *(const float4*)(xr + 256 + k4 * 4);
            float4 x3 = *(const float4*)(xr + 384 + k4 * 4);
            float4 w0 = *(const float4*)&Ws[(4 * k4 + 0) * 32 + cg];
            float4 w1 = *(const float4*)&Ws[(4 * k4 + 1) * 32 + cg];
            float4 w2 = *(const float4*)&Ws[(4 * k4 + 2) * 32 + cg];
            float4 w3 = *(const float4*)&Ws[(4 * k4 + 3) * 32 + cg];
            fma4(a0, x0.x, w0); fma4(a0, x0.y, w1); fma4(a0, x0.z, w2); fma4(a0, x0.w, w3);
            fma4(a1, x1.x, w0); fma4(a1, x1.y, w1); fma4(a1, x1.z, w2); fma4(a1, x1.w, w3);
            fma4(a2, x2.x, w0); fma4(a2, x2.y, w1); fma4(a2, x2.z, w2); fma4(a2, x2.w, w3);
            fma4(a3, x3.x, w0); fma4(a3, x3.y, w1); fma4(a3, x3.z, w2); fma4(a3, x3.w, w3);
        }
        scl4(a0, dinv[n0]); scl4(a1, dinv[n0 + 1]); scl4(a2, dinv[n0 + 2]); scl4(a3, dinv[n0 + 3]);
        *(float4*)&h[(size_t)(n0 + 0) * 32 + cg] = a0;
        *(float4*)&h[(size_t)(n0 + 1) * 32 + cg] = a1;
        *(float4*)&h[(size_t)(n0 + 2) * 32 + cg] = a2;
        *(float4*)&h[(size_t)(n0 + 3) * 32 + cg] = a3;
    } else {
        for (int nn = 0; nn < 4; ++nn) {
            int n = n0 + nn; if (n >= N) break;
            float4 a = {0,0,0,0};
            for (int k = 0; k < 128; ++k)
                fma4(a, x[(size_t)n * 128 + k], *(const float4*)&Ws[k * 32 + cg]);
            scl4(a, dinv[n]);
            *(float4*)&h[(size_t)n * 32 + cg] = a;
        }
    }
}

// h'[N][32] = (xc[:, colOff:colOff+32] @ W[32][32]) * dinv[n]   (xc row stride XCS)
__global__ void gemm32_32v(const float* __restrict__ xc, int colOff,
                           const float* __restrict__ W, const float* __restrict__ dinv,
                           float* __restrict__ h, int N) {
    __shared__ float Ws[32 * 32];
    int t = threadIdx.x;
    for (int i = t; i < 32 * 32; i += 256) Ws[i] = W[i];
    __syncthreads();
    int cg = (t & 7) * 4;
    int n0 = blockIdx.x * 128 + (t >> 3) * 4;
    if (n0 >= N) return;
    if (n0 + 4 <= N) {
        const float* xr = xc + (size_t)n0 * XCS + colOff;
        float4 a0 = {0,0,0,0}, a1 = a0, a2 = a0, a3 = a0;
#pragma unroll
        for (int k4 = 0; k4 < 8; ++k4) {
            float4 x0 = *(const float4*)(xr + k4 * 4);
            float4 x1 = *(const float4*)(xr + XCS + k4 * 4);
            float4 x2 = *(const float4*)(xr + 2 * XCS + k4 * 4);
            float4 x3 = *(const float4*)(xr + 3 * XCS + k4 * 4);
            float4 w0 = *(const float4*)&Ws[(4 * k4 + 0) * 32 + cg];
            float4 w1 = *(const float4*)&Ws[(4 * k4 + 1) * 32 + cg];
            float4 w2 = *(const float4*)&Ws[(4 * k4 + 2) * 32 + cg];
            float4 w3 = *(const float4*)&Ws[(4 * k4 + 3) * 32 + cg];
            fma4(a0, x0.x, w0); fma4(a0, x0.y, w1); fma4(a0, x0.z, w2); fma4(a0, x0.w, w3);
            fma4(a1, x1.x, w0); fma4(a1, x1.y, w1); fma4(a1, x1.z, w2); fma4(a1, x1.w, w3);
            fma4(a2, x2.x, w0); fma4(a2, x2.y, w1); fma4(a2, x2.z, w2); fma4(a2, x2.w, w3);
            fma4(a3, x3.x, w0); fma4(a3, x3.y, w1); fma4(a3, x3.z, w2); fma4(a3, x3.w, w3);
        }
        scl4(a0, dinv[n0]); scl4(a1, dinv[n0 + 1]); scl4(a2, dinv[n0 + 2]); scl4(a3, dinv[n0 + 3]);
        *(float4*)&h[(size_t)(n0 + 0) * 32 + cg] = a0;
        *(float4*)&h[(size_t)(n0 + 1) * 32 + cg] = a1;
        *(float4*)&h[(size_t)(n0 + 2) * 32 + cg] = a2;
        *(float4*)&h[(size_t)(n0 + 3) * 32 + cg] = a3;
    } else {
        for (int nn = 0; nn < 4; ++nn) {
            int n = n0 + nn; if (n >= N) break;
            float4 a = {0,0,0,0};
            for (int k = 0; k < 32; ++k)
                fma4(a, xc[(size_t)n * XCS + colOff + k], *(const float4*)&Ws[k * 32 + cg]);
            scl4(a, dinv[n]);
            *(float4*)&h[(size_t)n * 32 + cg] = a;
        }
    }
}

// hv'[N] = (xc[:, colOff:colOff+32] @ W4[32]) * dinv[n]
__global__ void gemm32_1(const float* __restrict__ xc, int colOff,
                         const float* __restrict__ W4, const float* __restrict__ dinv,
                         float* __restrict__ hv, int N) {
    __shared__ float W4s[32];
    int t = threadIdx.x;
    if (t < 32) W4s[t] = W4[t];
    __syncthreads();
    int n = blockIdx.x * 256 + t;
    if (n >= N) return;
    const float* xr = xc + (size_t)n * XCS + colOff;
    float a = 0.f;
#pragma unroll
    for (int k4 = 0; k4 < 8; ++k4) {
        float4 xv = *(const float4*)(xr + k4 * 4);
        a += xv.x * W4s[4 * k4] + xv.y * W4s[4 * k4 + 1]
           + xv.z * W4s[4 * k4 + 2] + xv.w * W4s[4 * k4 + 3];
    }
    hv[n] = a * dinv[n];
}

// ---------------- aggregation (gather, float4, 8 lanes per node) ----------------
// h is pre-scaled by dinv: out = tanh(dn * (h'[n] + sum h'[s]) + b)

__global__ void agg32v(const float* __restrict__ h, const int* __restrict__ off,
                       const int* __restrict__ eby, const float* __restrict__ dinv,
                       const float* __restrict__ b, float* __restrict__ xc, int colOff, int N) {
    int idx = blockIdx.x * 256 + threadIdx.x;
    int n = idx >> 3, q = idx & 7;       // q: which float4 of the 32-ch row
    if (n >= N) return;
    const float4* h4 = (const float4*)h;
    float dn = dinv[n];
    float4 acc = h4[(size_t)n * 8 + q];
    float4 acc2 = {0, 0, 0, 0};
    int e0 = off[n], e1 = off[n + 1];
    int j = e0;
    for (; j + 1 < e1; j += 2) {
        int s0 = eby[j], s1 = eby[j + 1];
        float4 h0 = h4[(size_t)s0 * 8 + q];
        float4 h1 = h4[(size_t)s1 * 8 + q];
        add4(acc, h0); add4(acc2, h1);
    }
    if (j < e1) add4(acc, h4[(size_t)eby[j] * 8 + q]);
    add4(acc, acc2);
    float4 bb = *(const float4*)&b[q * 4];
    float4 o;
    o.x = tanhf(acc.x * dn + bb.x);
    o.y = tanhf(acc.y * dn + bb.y);
    o.z = tanhf(acc.z * dn + bb.z);
    o.w = tanhf(acc.w * dn + bb.w);
    *(float4*)&xc[(size_t)n * XCS + colOff + q * 4] = o;
}

__global__ void agg1(const float* __restrict__ hv, const int* __restrict__ off,
                     const int* __restrict__ eby, const float* __restrict__ dinv,
                     const float* __restrict__ b4, float* __restrict__ xc, int N) {
    int n = blockIdx.x * 256 + threadIdx.x;
    if (n >= N) return;
    float dn = dinv[n];
    float acc = hv[n], acc2 = 0.f;
    int e0 = off[n], e1 = off[n + 1];
    int j = e0;
    for (; j + 1 < e1; j += 2) { acc += hv[eby[j]]; acc2 += hv[eby[j + 1]]; }
    if (j < e1) acc += hv[eby[j]];
    xc[(size_t)n * XCS + 96] = tanhf((acc + acc2) * dn + b4[0]);
}

// ---------------- fused head ----------------

__global__ void head_kernel(const float* __restrict__ xc,
                            const float* __restrict__ c5w, const float* __restrict__ c5b,
                            const float* __restrict__ c6w, const float* __restrict__ c6b,
                            const float* __restrict__ f1w, const float* __restrict__ f1b,
                            const float* __restrict__ f2w, const float* __restrict__ f2b,
                            float* __restrict__ out) {
    __shared__ float v[NPG];
    __shared__ int   ord[KK];
    __shared__ float topk[KK * FC];
    __shared__ float o5[16 * 30];
    __shared__ float p5[16 * 15];
    __shared__ float z[352];
    __shared__ float h1[128];
    __shared__ float lg[NC];
    __shared__ float lse;

    int g = blockIdx.x;
    int t = threadIdx.x;
    const float* xg = xc + (size_t)g * NPG * XCS;

    if (t < NPG) v[t] = xg[t * XCS + 96];
    __syncthreads();
    if (t < NPG) {
        float vi = v[t];
        int r = 0;
        for (int j = 0; j < NPG; ++j) {
            float vj = v[j];
            r += (vj > vi) || (vj == vi && j < t);  // stable descending rank
        }
        if (r < KK) ord[r] = t;
    }
    __syncthreads();
    for (int i = t; i < KK * FC; i += 128) {
        int r = i / FC, f = i - r * FC;
        topk[i] = xg[ord[r] * XCS + f];
    }
    __syncthreads();
    for (int i = t; i < 16 * 30; i += 128) {
        int ch = i / 30, tt = i - ch * 30;
        float a = c5b[ch];
        const float* w = c5w + ch * FC;
        const float* xx = topk + tt * FC;
        for (int f = 0; f < FC; ++f) a += xx[f] * w[f];
        o5[ch * 30 + tt] = fmaxf(a, 0.f);
    }
    __syncthreads();
    for (int i = t; i < 16 * 15; i += 128) {
        int ch = i / 15, tt = i - ch * 15;
        p5[i] = fmaxf(o5[ch * 30 + 2 * tt], o5[ch * 30 + 2 * tt + 1]);
    }
    __syncthreads();
    for (int i = t; i < 32 * 11; i += 128) {
        int oc = i / 11, tt = i - oc * 11;
        float a = c6b[oc];
#pragma unroll
        for (int ic = 0; ic < 16; ++ic) {
#pragma unroll
            for (int k = 0; k < 5; ++k)
                a += p5[ic * 15 + tt + k] * c6w[oc * 80 + ic * 5 + k];
        }
        z[oc * 11 + tt] = fmaxf(a, 0.f);
    }
    __syncthreads();
    {
        float a = f1b[t];
        for (int i = 0; i < 352; ++i) a += z[i] * f1w[i * 128 + t];
        h1[t] = fmaxf(a, 0.f);
    }
    __syncthreads();
    if (t < NC) {
        float a = f2b[t];
#pragma unroll
        for (int j = 0; j < 128; ++j) a += h1[j] * f2w[j * NC + t];
        lg[t] = a;
    }
    __syncthreads();
    if (t == 0) {
        float m = lg[0];
        for (int c = 1; c < NC; ++c) m = fmaxf(m, lg[c]);
        float s = 0.f;
        for (int c = 0; c < NC; ++c) s += expf(lg[c] - m);
        lse = m + logf(s);
    }
    __syncthreads();
    if (t < NC) out[(size_t)g * NC + t] = lg[t] - lse;
}

// ---------------- launch ----------------

static inline size_t align_up(size_t x, size_t a) { return (x + a - 1) & ~(a - 1); }

extern "C" void kernel_launch(void* const* d_in, const int* in_sizes, int n_in,
                              void* d_out, int out_size, void* d_ws, size_t ws_size,
                              hipStream_t stream) {
    const float* x   = (const float*)d_in[0];
    const int*   ei  = (const int*)d_in[1];
    const float* W1  = (const float*)d_in[3];
    const float* b1  = (const float*)d_in[4];
    const float* W2  = (const float*)d_in[5];
    const float* b2  = (const float*)d_in[6];
    const float* W3  = (const float*)d_in[7];
    const float* b3  = (const float*)d_in[8];
    const float* W4  = (const float*)d_in[9];
    const float* b4  = (const float*)d_in[10];
    const float* c5w = (const float*)d_in[11];
    const float* c5b = (const float*)d_in[12];
    const float* c6w = (const float*)d_in[13];
    const float* c6b = (const float*)d_in[14];
    const float* f1w = (const float*)d_in[15];
    const float* f1b = (const float*)d_in[16];
    const float* f2w = (const float*)d_in[17];
    const float* f2b = (const float*)d_in[18];
    float* out = (float*)d_out;

    const int N = in_sizes[0] / FIN;
    const int E = in_sizes[1] / 2;
    const int G = N / NPG;
    const int NB = (N + BKT_N - 1) >> BKT_SHIFT;  // buckets of 64 nodes
    const int NBLK = (E + CHA - 1) / CHA;         // sort blocks
    const int* src = ei;
    const int* dst = ei + E;

    // workspace plan (with lifetime unions):
    //  [colsum][boff][dinv][off][ ebuf | h ][ eby | cntmat ][ xcb | cntmatT ]
    //  cntmat:  written by sortA, read by transp, dead before bucketB writes eby
    //  cntmatT: written by transp, read by colsum_k/bucketB, dead before agg writes xcb
    //  ebuf:    written by sortA, read by bucketB, dead before gemm writes h
    char* ws = (char*)d_ws;
    size_t o = 0;
    int*   colsum = (int*)(ws + o); o = align_up(o + (size_t)NB * 4, 256);
    int*   boff   = (int*)(ws + o); o = align_up(o + (size_t)(NB + 1) * 4, 256);
    float* dinv   = (float*)(ws + o); o = align_up(o + (size_t)N * 4, 256);
    int*   off    = (int*)(ws + o); o = align_up(o + (size_t)(N + 1) * 4, 256);
    size_t big = (size_t)(E > N * 32 ? E : N * 32);
    int*   ebuf   = (int*)(ws + o); float* h = (float*)(ws + o);
    o = align_up(o + big * 4, 256);
    size_t big2 = (size_t)E * 4 > (size_t)NBLK * NB * 4 ? (size_t)E * 4 : (size_t)NBLK * NB * 4;
    int*   eby    = (int*)(ws + o); int* cntmat = (int*)(ws + o);
    o = align_up(o + big2, 256);
    size_t big3 = (size_t)N * XCS * 4 > (size_t)NBLK * NB * 4 ? (size_t)N * XCS * 4 : (size_t)NBLK * NB * 4;
    float* xcb    = (float*)(ws + o); int* cntmatT = (int*)(ws + o);
    o = align_up(o + big3, 256);
    (void)ws_size;

    int gbN  = (N + 255) / 256;
    int gbN8 = ((size_t)N * 8 + 255) / 256;
    int gbN128 = (N + 127) / 128;

    sortA<<<NBLK, 256, 0, stream>>>(src, dst, ebuf, cntmat, E, NB);
    dim3 tg((NB + TT - 1) / TT, (NBLK + TT - 1) / TT);
    transp<<<tg, 256, 0, stream>>>(cntmat, cntmatT, NBLK, NB);
    colsum_k<<<NB, 256, 0, stream>>>(cntmatT, colsum, NBLK);
    scan_nb<<<1, 256, 0, stream>>>(colsum, boff, off, NB, N, E);
    bucketB<<<NB, 256, 0, stream>>>(ebuf, cntmatT, boff, eby, off, dinv, N, NB, NBLK);

    // layer 1: 128 -> 32
    gemm128_32v<<<gbN128, 256, 0, stream>>>(x, W1, dinv, h, N);
    agg32v<<<gbN8, 256, 0, stream>>>(h, off, eby, dinv, b1, xcb, 0, N);
    // layer 2: 32 -> 32
    gemm32_32v<<<gbN128, 256, 0, stream>>>(xcb, 0, W2, dinv, h, N);
    agg32v<<<gbN8, 256, 0, stream>>>(h, off, eby, dinv, b2, xcb, 32, N);
    // layer 3: 32 -> 32
    gemm32_32v<<<gbN128, 256, 0, stream>>>(xcb, 32, W3, dinv, h, N);
    agg32v<<<gbN8, 256, 0, stream>>>(h, off, eby, dinv, b3, xcb, 64, N);
    // layer 4: 32 -> 1
    gemm32_1<<<gbN, 256, 0, stream>>>(xcb, 64, W4, dinv, h, N);
    agg1<<<gbN, 256, 0, stream>>>(h, off, eby, dinv, b4, xcb, N);

    // head
    head_kernel<<<G, 128, 0, stream>>>(xcb, c5w, c5b, c6w, c6b, f1w, f1b, f2w, f2b, out);
}